// Round 1
// baseline (1543.670 us; speedup 1.0000x reference)
//
#include <hip/hip_runtime.h>
#include <hip/hip_cooperative_groups.h>
#include <math.h>

namespace cg = cooperative_groups;

#define NB 4
#define NN 1024
#define ND 128
#define NUM_IN 64
#define F_EPS 1e-8f
#define BT_SCALE 1.8477590650225735f      // sqrt(2+sqrt(2))
#define INV_SQRT_D 0.08838834764831844f   // 1/sqrt(128)
#define OUT_STRIDE 256
#define A_OFF 1048576                     // floats: NB*NN*OUT_STRIDE

__device__ __forceinline__ float buntanh_f(float x) {
    return BT_SCALE * (0.5f * x + 0.5f * tanhf(x));
}

// ---------------- kernel 1: per-node matvecs -> prediction, K, Q ----------------
// grid = 3*4096 blocks; task>>12: 0 -> w1 -> prediction, 1 -> w2 -> K, 2 -> w3 -> Q
__global__ __launch_bounds__(256) void qkp_kernel(
    const float* __restrict__ state,
    const float* __restrict__ w1,
    const float* __restrict__ w2,
    const float* __restrict__ w3,
    float* __restrict__ dout,
    float* __restrict__ Qg,
    float* __restrict__ Kg)
{
    const int task = blockIdx.x;
    const int which = task >> 12;
    const int node = task & 4095;            // b*NN + n
    const float* w = (which == 0) ? w1 : ((which == 1) ? w2 : w3);
    const float4* w4 = (const float4*)(w + (size_t)node * (ND * ND));

    __shared__ float s_state[ND];
    __shared__ float4 red[8][32];

    const int t = threadIdx.x;
    if (t < ND) s_state[t] = state[(size_t)node * ND + t];
    __syncthreads();

    const int kq = t & 31;   // float4 column group: k = 4*kq..4*kq+3
    const int dg = t >> 5;   // d group: d in [dg*16, dg*16+16)
    float4 acc = make_float4(0.f, 0.f, 0.f, 0.f);
    #pragma unroll
    for (int i = 0; i < 16; ++i) {
        const int d = dg * 16 + i;
        const float s = s_state[d];
        const float4 wv = w4[d * 32 + kq];
        acc.x += s * wv.x; acc.y += s * wv.y;
        acc.z += s * wv.z; acc.w += s * wv.w;
    }
    red[dg][kq] = acc;
    __syncthreads();
    if (t < 32) {
        float4 o = red[0][t];
        #pragma unroll
        for (int g = 1; g < 8; ++g) {
            const float4 r = red[g][t];
            o.x += r.x; o.y += r.y; o.z += r.z; o.w += r.w;
        }
        o.x = buntanh_f(o.x); o.y = buntanh_f(o.y);
        o.z = buntanh_f(o.z); o.w = buntanh_f(o.w);
        if (which == 0) {
            *(float4*)(dout + (size_t)node * OUT_STRIDE + ND + 4 * t) = o;
        } else {
            float* base = (which == 1) ? Kg : Qg;
            *(float4*)(base + (size_t)node * ND + 4 * t) = o;
        }
    }
}

// ---------------- kernel 2: cooperative fused pipeline ----------------
// 512 blocks x 256 threads; block owns 8 rows of A for batch b = blockIdx>>7.
__global__ __launch_bounds__(256, 2) void triad_coop(
    const float* __restrict__ A_ema,
    const float* __restrict__ outp,
    const float* __restrict__ noise,
    const float* __restrict__ env,
    const float* __restrict__ Qg,
    const float* __restrict__ Kg,
    float* __restrict__ Vg,
    float* __restrict__ reds,   // [0..3] rms ssq, [4..7] var sum, [8..11] var sumsq
    float* __restrict__ CS,     // 3 x (NB*NN) column-sum buffers (zeroed before launch)
    float* __restrict__ dout)
{
    cg::grid_group grid = cg::this_grid();

    __shared__ float As[8][NN];    // 32 KB: this block's 8 rows of A
    __shared__ float Qs[8][132];   // padded to 132 floats (16B aligned rows)
    __shared__ float Ks[32][132];
    __shared__ float rsum[8];
    __shared__ float wred[8];

    const int t = threadIdx.x;
    const int b = blockIdx.x >> 7;
    const int r0 = (blockIdx.x & 127) << 3;

    // ---- phase 1: raw_A tile = Q(rows) @ K^T / sqrt(D), accumulate sum(raw^2) ----
    for (int i = t; i < 8 * ND; i += 256) {
        const int r = i >> 7, d = i & 127;
        Qs[r][d] = Qg[((size_t)(b * NN + r0 + r)) * ND + d];
    }
    __syncthreads();

    float ssq = 0.f;
    const int rr = t >> 5;   // 0..7
    const int ml = t & 31;   // 0..31
    for (int mt = 0; mt < 32; ++mt) {
        for (int i = t; i < 32 * ND; i += 256) {
            const int m = i >> 7, d = i & 127;
            Ks[m][d] = Kg[((size_t)(b * NN + mt * 32 + m)) * ND + d];
        }
        __syncthreads();
        const float4* q4 = (const float4*)Qs[rr];
        const float4* k4 = (const float4*)Ks[ml];
        float acc = 0.f;
        #pragma unroll
        for (int dq = 0; dq < 32; ++dq) {
            const float4 q = q4[dq];
            const float4 k = k4[dq];
            acc += q.x * k.x + q.y * k.y + q.z * k.z + q.w * k.w;
        }
        acc *= INV_SQRT_D;
        As[rr][mt * 32 + ml] = acc;
        ssq += acc * acc;
        __syncthreads();
    }

    for (int off = 32; off > 0; off >>= 1) ssq += __shfl_down(ssq, off, 64);
    if ((t & 63) == 0) wred[t >> 6] = ssq;
    __syncthreads();
    if (t == 0) atomicAdd(&reds[b], wred[0] + wred[1] + wred[2] + wred[3]);

    grid.sync();   // rms sum ready

    // ---- phase 2: rms scale + EMA + input-row mask + sinkhorn eps ----
    {
        const float ms = reds[b] * (1.0f / 1048576.0f);
        const float scale = rsqrtf(ms + F_EPS);
        for (int r = 0; r < 8; ++r) {
            const int gr = r0 + r;
            const float* ema_row = A_ema + ((size_t)(b * NN + gr)) * NN;
            for (int c = t; c < NN; c += 256) {
                float ema = ema_row[c];
                if (gr == NUM_IN && c < NUM_IN) ema += 3.0f / NUM_IN;
                float v = ema * 0.99f + (As[r][c] * scale) * 0.01f;
                if (gr < NUM_IN) v = 0.f;
                As[r][c] = fmaxf(v, 0.f) + F_EPS;
            }
        }
    }
    __syncthreads();

    // ---- sinkhorn: 2 calls x 8 iters; threshold+eps between (it==8) ----
    const float baseline = 1.0f / (NN + 1.0f);
    for (int it = 0; it < 16; ++it) {
        if (it == 8) {
            for (int r = 0; r < 8; ++r)
                for (int c = t; c < NN; c += 256) {
                    const float v = As[r][c];
                    As[r][c] = (v > baseline ? v : 0.f) + F_EPS;
                }
            __syncthreads();
        }
        // row sums (32 lanes per row)
        {
            const int r = t >> 5, l = t & 31;
            float s = 0.f;
            #pragma unroll
            for (int k = 0; k < 32; ++k) s += As[r][l + (k << 5)];
            for (int off = 16; off > 0; off >>= 1) s += __shfl_down(s, off, 32);
            if (l == 0) rsum[r] = s;
        }
        __syncthreads();
        const int cur = it % 3;
        float* csb = CS + cur * (NB * NN) + b * NN;
        // row divide + column partial sums (one atomic per column per block)
        for (int c = t; c < NN; c += 256) {
            float p = 0.f;
            #pragma unroll
            for (int r = 0; r < 8; ++r) {
                const float v = As[r][c] * (1.0f / rsum[r]);
                As[r][c] = v;
                p += v;
            }
            atomicAdd(&csb[c], p);
        }
        grid.sync();   // column sums complete
        for (int c = t; c < NN; c += 256) {
            const float sinv = 1.0f / csb[c];
            #pragma unroll
            for (int r = 0; r < 8; ++r) As[r][c] *= sinv;
        }
        // zero buffer for iteration it+3 (triple buffering keeps this race-free)
        if (t < 8) CS[((it + 2) % 3) * (NB * NN) + blockIdx.x * 8 + t] = 0.f;
        __syncthreads();
    }

    // ---- mask rows < NUM_IN, accumulate variance sums of final A ----
    const bool masked = (r0 < NUM_IN);
    float s1 = 0.f, s2 = 0.f;
    if (masked) {
        for (int r = 0; r < 8; ++r)
            for (int c = t; c < NN; c += 256) As[r][c] = 0.f;
    } else {
        for (int r = 0; r < 8; ++r)
            for (int c = t; c < NN; c += 256) {
                const float v = As[r][c];
                s1 += v; s2 += v * v;
            }
    }
    for (int off = 32; off > 0; off >>= 1) {
        s1 += __shfl_down(s1, off, 64);
        s2 += __shfl_down(s2, off, 64);
    }
    __syncthreads();
    if ((t & 63) == 0) { wred[t >> 6] = s1; wred[4 + (t >> 6)] = s2; }
    __syncthreads();
    if (t == 0) {
        atomicAdd(&reds[4 + b], wred[0] + wred[1] + wred[2] + wred[3]);
        atomicAdd(&reds[8 + b], wred[4] + wred[5] + wred[6] + wred[7]);
    }
    grid.sync();   // variance sums ready

    // ---- V = output + relu(0.02 - var) * noise (this block's 8 rows) ----
    {
        const float M = 1048576.0f;
        const float S1 = reds[4 + b], S2 = reds[8 + b];
        const float var = (S2 - S1 * S1 / M) / (M - 1.0f);   // ddof=1
        const float vd = fmaxf(0.02f - var, 0.f);
        for (int i = t; i < 8 * ND; i += 256) {
            const int r = i >> 7, d = i & 127;
            const size_t idx = ((size_t)(b * NN + r0 + r)) * ND + d;
            Vg[idx] = outp[idx] + vd * noise[idx];
        }
    }
    grid.sync();   // V ready

    // ---- target rows: softsign(A @ V), or env overwrite for input rows ----
    if (masked) {
        for (int i = t; i < 8 * ND; i += 256) {
            const int r = i >> 7, d = i & 127;
            dout[((size_t)(b * NN + r0 + r)) * OUT_STRIDE + d] =
                env[(size_t)b * 8192 + (size_t)(r0 + r) * ND + d];
        }
    } else {
        const int d = t & 127;
        const int rg = t >> 7;        // 0..1
        const int rbase = rg * 4;
        const float* Vb = Vg + (size_t)b * NN * ND + d;
        float a0 = 0.f, a1 = 0.f, a2 = 0.f, a3 = 0.f;
        #pragma unroll 8
        for (int m = 0; m < NN; ++m) {
            const float vv = Vb[(size_t)m * ND];
            a0 += As[rbase + 0][m] * vv;
            a1 += As[rbase + 1][m] * vv;
            a2 += As[rbase + 2][m] * vv;
            a3 += As[rbase + 3][m] * vv;
        }
        const size_t ob = ((size_t)(b * NN + r0 + rbase)) * OUT_STRIDE + d;
        dout[ob]                  = a0 / (1.f + fabsf(a0));
        dout[ob + OUT_STRIDE]     = a1 / (1.f + fabsf(a1));
        dout[ob + 2 * OUT_STRIDE] = a2 / (1.f + fabsf(a2));
        dout[ob + 3 * OUT_STRIDE] = a3 / (1.f + fabsf(a3));
    }
    grid.sync();   // all V reads done; safe to overwrite scratch region with A

    // ---- write final A ----
    for (int r = 0; r < 8; ++r) {
        float* arow = dout + A_OFF + ((size_t)(b * NN + r0 + r)) * NN;
        for (int c = t; c < NN; c += 256) arow[c] = As[r][c];
    }
}

extern "C" void kernel_launch(void* const* d_in, const int* in_sizes, int n_in,
                              void* d_out, int out_size, void* d_ws, size_t ws_size,
                              hipStream_t stream)
{
    (void)in_sizes; (void)n_in; (void)out_size; (void)d_ws; (void)ws_size;
    const float* state = (const float*)d_in[0];
    const float* outp  = (const float*)d_in[1];
    const float* w1    = (const float*)d_in[2];
    const float* w2    = (const float*)d_in[3];
    const float* w3    = (const float*)d_in[4];
    const float* A_ema = (const float*)d_in[5];
    const float* env   = (const float*)d_in[6];
    const float* noise = (const float*)d_in[7];
    float* dout = (float*)d_out;

    // Scratch carved from d_out's A-region (written only at the very end):
    // Q (512K) | K (512K) | V (512K) | reds (16) | CS (3*4096)
    float* Qg   = dout + A_OFF;
    float* Kg   = Qg + NB * NN * ND;
    float* Vg   = Kg + NB * NN * ND;
    float* reds = Vg + NB * NN * ND;
    float* CS   = reds + 16;

    hipMemsetAsync(reds, 0, (16 + 3 * NB * NN) * sizeof(float), stream);

    qkp_kernel<<<dim3(3 * NB * NN), dim3(256), 0, stream>>>(
        state, w1, w2, w3, dout, Qg, Kg);

    void* args[] = {
        (void*)&A_ema, (void*)&outp, (void*)&noise, (void*)&env,
        (void*)&Qg, (void*)&Kg, (void*)&Vg, (void*)&reds, (void*)&CS, (void*)&dout
    };
    hipLaunchCooperativeKernel((void*)triad_coop, dim3(512), dim3(256),
                               args, 0, stream);
}

// Round 2
// 590.233 us; speedup vs baseline: 2.6154x; 2.6154x over previous
//
#include <hip/hip_runtime.h>
#include <math.h>

#define NB 4
#define NN 1024
#define ND 128
#define NUM_IN 64
#define F_EPS 1e-8f
#define BT_SCALE 1.8477590650225735f      // sqrt(2+sqrt(2))
#define INV_SQRT_D 0.08838834764831844f   // 1/sqrt(128)
#define BASELINE (1.0f/1025.0f)
#define OUT_STRIDE 256
#define A_OFF 1048576                     // floats: NB*NN*OUT_STRIDE

__device__ __forceinline__ float buntanh_f(float x) {
    return BT_SCALE * (0.5f * x + 0.5f * tanhf(x));
}

__device__ __forceinline__ float wave_sum(float v) {
    #pragma unroll
    for (int off = 32; off > 0; off >>= 1) v += __shfl_xor(v, off, 64);
    return v;
}

// ---------- K1: per-node matvecs -> prediction (d_out), K, Q (d_ws) ----------
__global__ __launch_bounds__(256) void qkp_kernel(
    const float* __restrict__ state,
    const float* __restrict__ w1,
    const float* __restrict__ w2,
    const float* __restrict__ w3,
    float* __restrict__ dout,
    float* __restrict__ Qg,
    float* __restrict__ Kg)
{
    const int task = blockIdx.x;
    const int which = task >> 12;
    const int node = task & 4095;            // b*NN + n
    const float* w = (which == 0) ? w1 : ((which == 1) ? w2 : w3);
    const float4* w4 = (const float4*)(w + (size_t)node * (ND * ND));

    __shared__ float s_state[ND];
    __shared__ float4 red[8][32];

    const int t = threadIdx.x;
    if (t < ND) s_state[t] = state[(size_t)node * ND + t];
    __syncthreads();

    const int kq = t & 31;
    const int dg = t >> 5;
    float4 acc = make_float4(0.f, 0.f, 0.f, 0.f);
    #pragma unroll
    for (int i = 0; i < 16; ++i) {
        const int d = dg * 16 + i;
        const float s = s_state[d];
        const float4 wv = w4[d * 32 + kq];
        acc.x += s * wv.x; acc.y += s * wv.y;
        acc.z += s * wv.z; acc.w += s * wv.w;
    }
    red[dg][kq] = acc;
    __syncthreads();
    if (t < 32) {
        float4 o = red[0][t];
        #pragma unroll
        for (int g = 1; g < 8; ++g) {
            const float4 r = red[g][t];
            o.x += r.x; o.y += r.y; o.z += r.z; o.w += r.w;
        }
        o.x = buntanh_f(o.x); o.y = buntanh_f(o.y);
        o.z = buntanh_f(o.z); o.w = buntanh_f(o.w);
        if (which == 0) {
            *(float4*)(dout + (size_t)node * OUT_STRIDE + ND + 4 * t) = o;
        } else {
            float* base = (which == 1) ? Kg : Qg;
            *(float4*)(base + (size_t)node * ND + 4 * t) = o;
        }
    }
}

// ---------- K2: raw_A = Q K^T * inv_sqrt_d -> M (d_out A-region); ssq atomics ----------
__global__ __launch_bounds__(256) void qk2_kernel(
    const float* __restrict__ Qg, const float* __restrict__ Kg,
    float* __restrict__ Rg, float* __restrict__ reds)
{
    const int b = blockIdx.x >> 10;
    const int tile = blockIdx.x & 1023;
    const int tr = tile >> 5, tc = tile & 31;

    __shared__ float Qs[32][132];
    __shared__ float Ks[32][132];
    __shared__ float wr[4];

    const int t = threadIdx.x;
    for (int i = t; i < 1024; i += 256) {     // 32 rows x 32 float4
        const int r = i >> 5, q = i & 31;
        *(float4*)&Qs[r][q*4] = *(const float4*)(Qg + (((size_t)(b*NN + tr*32 + r)) << 7) + q*4);
        *(float4*)&Ks[r][q*4] = *(const float4*)(Kg + (((size_t)(b*NN + tc*32 + r)) << 7) + q*4);
    }
    __syncthreads();

    const int ty = t >> 4, tx = t & 15;       // rows ty,ty+16 ; cols tx,tx+16
    float a00=0.f, a01=0.f, a10=0.f, a11=0.f;
    #pragma unroll
    for (int dq = 0; dq < 32; ++dq) {
        const float4 q0 = *(const float4*)&Qs[ty][dq*4];
        const float4 q1 = *(const float4*)&Qs[ty+16][dq*4];
        const float4 k0 = *(const float4*)&Ks[tx][dq*4];
        const float4 k1 = *(const float4*)&Ks[tx+16][dq*4];
        a00 += q0.x*k0.x + q0.y*k0.y + q0.z*k0.z + q0.w*k0.w;
        a01 += q0.x*k1.x + q0.y*k1.y + q0.z*k1.z + q0.w*k1.w;
        a10 += q1.x*k0.x + q1.y*k0.y + q1.z*k0.z + q1.w*k0.w;
        a11 += q1.x*k1.x + q1.y*k1.y + q1.z*k1.z + q1.w*k1.w;
    }
    a00 *= INV_SQRT_D; a01 *= INV_SQRT_D; a10 *= INV_SQRT_D; a11 *= INV_SQRT_D;
    const size_t row0 = (size_t)(b*NN + tr*32 + ty) * NN + tc*32;
    const size_t row1 = (size_t)(b*NN + tr*32 + ty + 16) * NN + tc*32;
    Rg[row0 + tx]      = a00;
    Rg[row0 + tx + 16] = a01;
    Rg[row1 + tx]      = a10;
    Rg[row1 + tx + 16] = a11;

    float ssq = a00*a00 + a01*a01 + a10*a10 + a11*a11;
    ssq = wave_sum(ssq);
    if ((t & 63) == 0) wr[t >> 6] = ssq;
    __syncthreads();
    if (t == 0) atomicAdd(&reds[b], wr[0] + wr[1] + wr[2] + wr[3]);
}

// ---------- K3: EMA + mask + eps (elementwise, in-place on M) ----------
__global__ __launch_bounds__(256) void ema_kernel(
    const float* __restrict__ A_ema, const float* __restrict__ reds,
    float* __restrict__ M)
{
    const int i = blockIdx.x * 256 + threadIdx.x;   // float4 index, 1048576 total
    const int b = i >> 18;
    const float scale = rsqrtf(reds[b] * (1.0f / 1048576.0f) + F_EPS);
    const int rc = i & 262143;
    const int r = rc >> 8;
    const int c0 = (rc & 255) * 4;

    float4 raw = ((const float4*)M)[i];
    float4 e   = ((const float4*)A_ema)[i];
    float o[4];
    const float* rawp = (const float*)&raw;
    const float* ep   = (const float*)&e;
    #pragma unroll
    for (int j = 0; j < 4; ++j) {
        float em = ep[j];
        if (r == NUM_IN && (c0 + j) < NUM_IN) em += 3.0f / NUM_IN;
        float v = em * 0.99f + (rawp[j] * scale) * 0.01f;
        if (r < NUM_IN) v = 0.f;
        o[j] = fmaxf(v, 0.f) + F_EPS;
    }
    ((float4*)M)[i] = make_float4(o[0], o[1], o[2], o[3]);
}

// ---------- K4 x16: one Sinkhorn normalize step ----------
// variant 0: first (no pending col divisor); 1: normal; 2: threshold+eps after col-div
__global__ __launch_bounds__(256) void sink_iter(
    float* __restrict__ M, const float* __restrict__ Pin,
    float* __restrict__ Pout, int variant)
{
    __shared__ float invt[NN];
    __shared__ float colp[NN];
    const int t = threadIdx.x;
    const int b = blockIdx.x >> 6;
    const int pb = blockIdx.x & 63;
    const int r0 = pb << 4;

    #pragma unroll
    for (int c = 0; c < 4; ++c) colp[t + 256*c] = 0.f;

    if (variant != 0) {
        float s0=0.f, s1=0.f, s2=0.f, s3=0.f;
        const float* Pb = Pin + (size_t)b * 65536;
        #pragma unroll 4
        for (int p = 0; p < 64; ++p) {
            const float* row = Pb + p * NN + t;
            s0 += row[0]; s1 += row[256]; s2 += row[512]; s3 += row[768];
        }
        invt[t]       = 1.f / s0;
        invt[t + 256] = 1.f / s1;
        invt[t + 512] = 1.f / s2;
        invt[t + 768] = 1.f / s3;
    } else {
        #pragma unroll
        for (int c = 0; c < 4; ++c) invt[t + 256*c] = 1.f;
    }
    __syncthreads();

    const int l = t & 63;
    const int w = t >> 6;
    float p[16];
    #pragma unroll
    for (int c = 0; c < 16; ++c) p[c] = 0.f;

    for (int rr = 0; rr < 4; ++rr) {
        const int r = r0 + w*4 + rr;
        float* Mrow = M + ((size_t)(b*NN + r) << 10);
        float a[16];
        float s = 0.f;
        if (variant == 2) {
            #pragma unroll
            for (int c = 0; c < 16; ++c) {
                const int j = c*64 + l;
                const float d = Mrow[j] * invt[j];
                a[c] = (d > BASELINE ? d : 0.f) + F_EPS;
                s += a[c];
            }
        } else {
            #pragma unroll
            for (int c = 0; c < 16; ++c) {
                const int j = c*64 + l;
                a[c] = Mrow[j] * invt[j];
                s += a[c];
            }
        }
        s = wave_sum(s);
        const float is = 1.f / s;
        #pragma unroll
        for (int c = 0; c < 16; ++c) {
            const int j = c*64 + l;
            const float o = a[c] * is;
            Mrow[j] = o;
            p[c] += o;
        }
    }
    #pragma unroll
    for (int c = 0; c < 16; ++c) atomicAdd(&colp[c*64 + l], p[c]);
    __syncthreads();
    float* Po = Pout + (size_t)(b*64 + pb) * NN;
    #pragma unroll
    for (int c = 0; c < 4; ++c) Po[t + 256*c] = colp[t + 256*c];
}

// ---------- K5: final col-div + row mask + variance partials (in-place -> A) ----------
__global__ __launch_bounds__(256) void sink_fin(
    float* __restrict__ M, const float* __restrict__ Pin, float* __restrict__ reds)
{
    __shared__ float invt[NN];
    __shared__ float wr[8];
    const int t = threadIdx.x;
    const int b = blockIdx.x >> 6;
    const int pb = blockIdx.x & 63;
    const int r0 = pb << 4;

    {
        float s0=0.f, s1=0.f, s2=0.f, s3=0.f;
        const float* Pb = Pin + (size_t)b * 65536;
        #pragma unroll 4
        for (int p = 0; p < 64; ++p) {
            const float* row = Pb + p * NN + t;
            s0 += row[0]; s1 += row[256]; s2 += row[512]; s3 += row[768];
        }
        invt[t]       = 1.f / s0;
        invt[t + 256] = 1.f / s1;
        invt[t + 512] = 1.f / s2;
        invt[t + 768] = 1.f / s3;
    }
    __syncthreads();

    const int l = t & 63;
    const int w = t >> 6;
    float s1a = 0.f, s2a = 0.f;
    for (int rr = 0; rr < 4; ++rr) {
        const int r = r0 + w*4 + rr;
        float* Mrow = M + ((size_t)(b*NN + r) << 10);
        if (r0 < NUM_IN) {
            #pragma unroll
            for (int c = 0; c < 16; ++c) Mrow[c*64 + l] = 0.f;
        } else {
            #pragma unroll
            for (int c = 0; c < 16; ++c) {
                const int j = c*64 + l;
                const float o = Mrow[j] * invt[j];
                Mrow[j] = o;
                s1a += o; s2a += o*o;
            }
        }
    }
    s1a = wave_sum(s1a);
    s2a = wave_sum(s2a);
    if ((t & 63) == 0) { wr[t>>6] = s1a; wr[4 + (t>>6)] = s2a; }
    __syncthreads();
    if (t == 0) {
        atomicAdd(&reds[4 + b], wr[0] + wr[1] + wr[2] + wr[3]);
        atomicAdd(&reds[8 + b], wr[4] + wr[5] + wr[6] + wr[7]);
    }
}

// ---------- K6: V = output + relu(0.02 - var) * noise ----------
__global__ __launch_bounds__(256) void vbuild_kernel(
    const float* __restrict__ outp, const float* __restrict__ noise,
    const float* __restrict__ reds, float* __restrict__ V)
{
    const int i = blockIdx.x * 256 + threadIdx.x;   // float4 idx, 131072 total
    const int b = i >> 15;
    const float Mn = 1048576.f;
    const float S1 = reds[4 + b], S2 = reds[8 + b];
    const float var = (S2 - S1*S1/Mn) / (Mn - 1.f);
    const float vd = fmaxf(0.02f - var, 0.f);
    const float4 o = ((const float4*)outp)[i];
    const float4 n = ((const float4*)noise)[i];
    ((float4*)V)[i] = make_float4(o.x + vd*n.x, o.y + vd*n.y,
                                  o.z + vd*n.z, o.w + vd*n.w);
}

// ---------- K7: target = softsign(A @ V); env rows overwrite ----------
__global__ __launch_bounds__(256) void av_kernel(
    const float* __restrict__ A, const float* __restrict__ V,
    const float* __restrict__ env, float* __restrict__ dout)
{
    const int b = blockIdx.x >> 6;
    const int r0 = (blockIdx.x & 63) << 4;
    const int t = threadIdx.x;

    if (r0 < NUM_IN) {
        for (int i = t; i < 16 * ND; i += 256) {
            const int r = i >> 7, d = i & 127;
            dout[((size_t)(b*NN + r0 + r)) * OUT_STRIDE + d] =
                env[(size_t)b * 8192 + (size_t)(r0 + r) * ND + d];
        }
        return;
    }

    __shared__ float As[16][68];
    const int d  = t & 127;
    const int rg = t >> 7;
    float acc[8] = {0.f,0.f,0.f,0.f,0.f,0.f,0.f,0.f};
    const float* Vb = V + (size_t)b * (NN * ND) + d;

    for (int mt = 0; mt < 16; ++mt) {
        {
            const int r = t >> 4, mq = t & 15;
            *(float4*)&As[r][mq*4] =
                *(const float4*)(A + (((size_t)(b*NN + r0 + r)) << 10) + mt*64 + mq*4);
        }
        __syncthreads();
        #pragma unroll
        for (int m4 = 0; m4 < 16; ++m4) {
            float4 a4[8];
            #pragma unroll
            for (int k = 0; k < 8; ++k) a4[k] = *(const float4*)&As[rg*8 + k][m4*4];
            #pragma unroll
            for (int mm = 0; mm < 4; ++mm) {
                const float v = Vb[(size_t)(mt*64 + m4*4 + mm) * ND];
                #pragma unroll
                for (int k = 0; k < 8; ++k)
                    acc[k] += ((const float*)&a4[k])[mm] * v;
            }
        }
        __syncthreads();
    }
    #pragma unroll
    for (int k = 0; k < 8; ++k) {
        const float o = acc[k];
        dout[((size_t)(b*NN + r0 + rg*8 + k)) * OUT_STRIDE + d] = o / (1.f + fabsf(o));
    }
}

extern "C" void kernel_launch(void* const* d_in, const int* in_sizes, int n_in,
                              void* d_out, int out_size, void* d_ws, size_t ws_size,
                              hipStream_t stream)
{
    (void)in_sizes; (void)n_in; (void)out_size; (void)ws_size;
    const float* state = (const float*)d_in[0];
    const float* outp  = (const float*)d_in[1];
    const float* w1    = (const float*)d_in[2];
    const float* w2    = (const float*)d_in[3];
    const float* w3    = (const float*)d_in[4];
    const float* A_ema = (const float*)d_in[5];
    const float* env   = (const float*)d_in[6];
    const float* noise = (const float*)d_in[7];
    float* dout = (float*)d_out;
    float* M    = dout + A_OFF;               // 4M floats: raw_A -> sinkhorn M -> final A

    // d_ws layout (floats): Q | K | P0 | P1 | V | reds  (~8.4 MB)
    float* Qg   = (float*)d_ws;
    float* Kg   = Qg + NB*NN*ND;
    float* P0   = Kg + NB*NN*ND;
    float* P1   = P0 + NB*64*NN;
    float* Vg   = P1 + NB*64*NN;
    float* reds = Vg + NB*NN*ND;

    hipMemsetAsync(reds, 0, 12 * sizeof(float), stream);

    qkp_kernel<<<dim3(3 * NB * NN), dim3(256), 0, stream>>>(
        state, w1, w2, w3, dout, Qg, Kg);

    qk2_kernel<<<dim3(NB * 1024), dim3(256), 0, stream>>>(Qg, Kg, M, reds);

    ema_kernel<<<dim3(4096), dim3(256), 0, stream>>>(A_ema, reds, M);

    for (int k = 0; k < 16; ++k) {
        const int variant = (k == 0) ? 0 : ((k == 8) ? 2 : 1);
        float* Pin  = (k & 1) ? P0 : P1;   // buf[(k+1)&1]
        float* Pout = (k & 1) ? P1 : P0;   // buf[k&1]
        sink_iter<<<dim3(NB * 64), dim3(256), 0, stream>>>(M, Pin, Pout, variant);
    }

    sink_fin<<<dim3(NB * 64), dim3(256), 0, stream>>>(M, P1, reds);

    vbuild_kernel<<<dim3(512), dim3(256), 0, stream>>>(outp, noise, reds, Vg);

    av_kernel<<<dim3(NB * 64), dim3(256), 0, stream>>>(M, Vg, env, dout);
}